// Round 4
// baseline (519.546 us; speedup 1.0000x reference)
//
#include <hip/hip_runtime.h>
#include <hip/hip_bf16.h>

#define HIDDEN 768
#define NB 8
#define BLK 96
#define S_LEN 8192
#define H_LEN 4096
#define M_LEN 4097
#define MP 4160           // spectrum word pitch (65*64); one (r,i) bf16 word per mode
#define BATCH 4
#define KBIG 192          // 2*BLK (interleaved r/i channels)
#define TMOD 64           // modes per MLP workgroup
#define MPITCH 66         // act LDS row pitch in bf16 elems (33 words, odd -> conflict-free)

#define TWO_PI 6.28318530717958647692f
#define INV_SQRT_N 0.011048543456039806f   // 1/sqrt(8192)
#define C_INV 0.022097086912079612f        // 2/sqrt(8192)
#define LAM 0.01f

typedef __attribute__((ext_vector_type(8))) short short8;
typedef __attribute__((ext_vector_type(4))) float float4v;

__device__ __forceinline__ int rev12(int k) {
    return (int)(__brev((unsigned)k) >> 20);
}
__device__ __forceinline__ short f2bf(float f) {
    __hip_bfloat16 h = __float2bfloat16(f);
    return *reinterpret_cast<short*>(&h);
}
__device__ __forceinline__ float bf2f(unsigned short s) {
    __hip_bfloat16 h = *reinterpret_cast<__hip_bfloat16*>(&s);
    return __bfloat162float(h);
}

// ---------------------------------------------------------------------------
// P1: twiddle tables.
//   twf[4095]: stage-major butterfly twiddles. Stage s (half=2^s) occupies
//              [half-1, 2*half-1), entry j has ang = -2*pi*j/(2*half).
//   twu[4097]: pack/unpack twiddles, ang = -2*pi*m/8192.
// ---------------------------------------------------------------------------
__global__ __launch_bounds__(256) void prep_tables(float2* __restrict__ twf,
                                                   float2* __restrict__ twu) {
    int idx = blockIdx.x * 256 + threadIdx.x;
    if (idx < 4095) {
        int p = idx + 1;                       // in [1, 4096)
        int half = 1 << (31 - __clz(p));       // stage half-size
        int j = p - half;
        float ang = -TWO_PI * (float)j / (float)(2 * half);
        float sn, cs;
        sincosf(ang, &sn, &cs);
        twf[idx] = make_float2(cs, sn);
    }
    if (idx <= H_LEN) {
        float ang = -TWO_PI * (float)idx * (1.0f / (float)S_LEN);
        float sn, cs;
        sincosf(ang, &sn, &cs);
        twu[idx] = make_float2(cs, sn);
    }
}

// ---------------------------------------------------------------------------
// P0: build bf16 big-weight matrices WT[n][out=192][kin=192] (kin interleaved
// r/i) for both layers, plus concatenated biases (fp32).
// ---------------------------------------------------------------------------
__global__ __launch_bounds__(256) void prep_weights(const float* __restrict__ w1,
                                                    const float* __restrict__ w2,
                                                    const float* __restrict__ b1,
                                                    const float* __restrict__ b2,
                                                    short* __restrict__ WT1,
                                                    short* __restrict__ WT2,
                                                    float* __restrict__ bb1,
                                                    float* __restrict__ bb2) {
    int idx = blockIdx.x * 256 + threadIdx.x;
    if (idx < NB * KBIG * KBIG) {
        int n = idx / (KBIG * KBIG);
        int r = idx % (KBIG * KBIG);
        int o = r / KBIG;
        int kin = r % KBIG;
        int d = kin >> 1;
        int im = kin & 1;
        {
            float w0 = w1[((size_t)(0 * NB + n) * BLK + d) * BLK + (o < BLK ? o : o - BLK)];
            float wi = w1[((size_t)(1 * NB + n) * BLK + d) * BLK + (o < BLK ? o : o - BLK)];
            float v = (o < BLK) ? (im ? -wi : w0) : (im ? w0 : wi);
            WT1[idx] = f2bf(v);
        }
        {
            float w0 = w2[((size_t)(0 * NB + n) * BLK + d) * BLK + (o < BLK ? o : o - BLK)];
            float wi = w2[((size_t)(1 * NB + n) * BLK + d) * BLK + (o < BLK ? o : o - BLK)];
            float v = (o < BLK) ? (im ? -wi : w0) : (im ? w0 : wi);
            WT2[idx] = f2bf(v);
        }
    }
    if (idx < NB * KBIG) {
        int n = idx / KBIG, o = idx % KBIG;
        bb1[idx] = (o < BLK) ? b1[(0 * NB + n) * BLK + o] : b1[(1 * NB + n) * BLK + o - BLK];
        bb2[idx] = (o < BLK) ? b2[(0 * NB + n) * BLK + o] : b2[(1 * NB + n) * BLK + o - BLK];
    }
}

// ---------------------------------------------------------------------------
// K0: x [B,S,C] f32  ->  xT [B*C, S] bf16   (32x32 LDS tiles, coalesced)
// ---------------------------------------------------------------------------
__global__ __launch_bounds__(256) void transpose_in(const float* __restrict__ x,
                                                    __hip_bfloat16* __restrict__ xT) {
    __shared__ float t[32][33];
    const int cb = blockIdx.x, sb = blockIdx.y, b = blockIdx.z;
    const int tx = threadIdx.x & 31, ty = threadIdx.x >> 5;
    const float* xp = x + ((size_t)b * S_LEN + sb * 32) * HIDDEN + cb * 32;
    for (int i = 0; i < 4; i++)
        t[ty + 8 * i][tx] = xp[(size_t)(ty + 8 * i) * HIDDEN + tx];
    __syncthreads();
    __hip_bfloat16* xq = xT + ((size_t)b * HIDDEN + cb * 32) * S_LEN + sb * 32;
    for (int i = 0; i < 4; i++)
        xq[(size_t)(ty + 8 * i) * S_LEN + tx] = __float2bfloat16(t[tx][ty + 8 * i]);
}

// ---------------------------------------------------------------------------
// K1: forward rfft per (b,c) -> interleaved (r,i) bf16 words Xc[row][m]
// ---------------------------------------------------------------------------
__global__ __launch_bounds__(256) void fft_fwd(const __hip_bfloat16* __restrict__ xT,
                                               unsigned int* __restrict__ Xc,
                                               const float2* __restrict__ twf,
                                               const float2* __restrict__ twu) {
    __shared__ float sr[H_LEN];
    __shared__ float si[H_LEN];
    const int wg = blockIdx.x;           // b*HIDDEN + c
    const int tid = threadIdx.x;
    const __hip_bfloat162* xrow = (const __hip_bfloat162*)(xT + (size_t)wg * S_LEN);

    const int a = tid & 31, cb3 = tid >> 5;
    for (int it = 0; it < 16; it++) {
        int k = (a << 7) | (it << 3) | cb3;        // bijective over [0,4096)
        __hip_bfloat162 v = xrow[k];               // z[k] = x[2k] + i x[2k+1]
        int r = rev12(k);                          // bank = rev5(a): conflict-free
        sr[r] = __bfloat162float(v.x);
        si[r] = __bfloat162float(v.y);
    }
    __syncthreads();

    // 12 radix-2 DIT stages, forward (e^{-i}), table twiddles
    for (int s = 0; s < 12; s++) {
        const int half = 1 << s;
        const float2* tws = twf + (half - 1);
        for (int i = tid; i < H_LEN / 2; i += 256) {
            int j = i & (half - 1);
            int i1 = ((i - j) << 1) + j;
            int i2 = i1 + half;
            float2 wv = tws[j];
            float wcs = wv.x, wsn = wv.y;
            float ur = sr[i1], ui = si[i1];
            float vr = sr[i2], vi = si[i2];
            float tr = vr * wcs - vi * wsn;
            float ti = vr * wsn + vi * wcs;
            sr[i1] = ur + tr; si[i1] = ui + ti;
            sr[i2] = ur - tr; si[i2] = ui - ti;
        }
        __syncthreads();
    }

    unsigned int* Xrow = Xc + (size_t)wg * MP;
    for (int m = tid; m <= H_LEN; m += 256) {
        int ia = m & (H_LEN - 1);
        int ib = (H_LEN - m) & (H_LEN - 1);
        float ar = sr[ia], ai = si[ia];
        float br = sr[ib], bi = si[ib];
        float er = 0.5f * (ar + br), ei = 0.5f * (ai - bi);
        float dr = ar - br, di = ai + bi;
        float or_ = 0.5f * di, oi = -0.5f * dr;
        float2 tv = twu[m];
        float wcs = tv.x, wsn = tv.y;
        float xrv = (er + wcs * or_ - wsn * oi) * INV_SQRT_N;
        float xiv = (ei + wcs * oi + wsn * or_) * INV_SQRT_N;
        unsigned wd = (unsigned short)f2bf(xrv) | ((unsigned)(unsigned short)f2bf(xiv) << 16);
        Xrow[m] = wd;
    }
}

// ---------------------------------------------------------------------------
// K2: MFMA block-diagonal complex MLP, in place over Xc.
// ---------------------------------------------------------------------------
__global__ __launch_bounds__(256) void mlp_mfma(const short* __restrict__ WT1,
                                                const short* __restrict__ WT2,
                                                const float* __restrict__ bb1,
                                                const float* __restrict__ bb2,
                                                unsigned int* __restrict__ Xc) {
    __shared__ short actA[KBIG * MPITCH];  // input, later final output
    __shared__ short actB[KBIG * MPITCH];  // layer-1 output
    const int tid = threadIdx.x;
    const int chunk = blockIdx.x;          // 0..64
    const int n = blockIdx.y;
    const int b = blockIdx.z;
    const int m0 = chunk * TMOD;
    unsigned int* __restrict__ Xrow0 =
        Xc + ((size_t)b * HIDDEN + (size_t)n * BLK) * MP + m0;

    // ---- stage: 96 channel rows x 64 modes, de-interleave to rows 2d / 2d+1
    {
        const int mw = tid & 31;           // word-pair: modes 2mw, 2mw+1
        const int dr = tid >> 5;           // 0..7
        int* a32 = (int*)actA;
        for (int pass = 0; pass < 12; pass++) {
            int d = dr + pass * 8;
            const uint2* src = (const uint2*)(Xrow0 + (size_t)d * MP);
            uint2 v = src[mw];
            unsigned rw = (v.x & 0xFFFFu) | (v.y << 16);
            unsigned iw = (v.x >> 16) | (v.y & 0xFFFF0000u);
            a32[(2 * d) * 33 + mw] = (int)rw;
            a32[(2 * d + 1) * 33 + mw] = (int)iw;
        }
    }
    __syncthreads();

    const int w = tid >> 6;
    const int l15 = tid & 15;
    const int q = (tid >> 4) & 3;
    const int outw = w * 48;

    // ---- layer 1 ----
    short8 wf[3][6];
    for (int nl = 0; nl < 3; nl++)
        for (int ks = 0; ks < 6; ks++)
            wf[nl][ks] = *(const short8*)(WT1 + ((size_t)n * KBIG + outw + nl * 16 + l15) * KBIG + ks * 32 + q * 8);

    for (int mt = 0; mt < 4; mt++) {
        float4v acc[3];
        for (int nl = 0; nl < 3; nl++)
            acc[nl] = *(const float4v*)(bb1 + n * KBIG + outw + nl * 16 + q * 4);
        for (int ks = 0; ks < 6; ks++) {
            short8 bf;
            const short* base = actA + (ks * 32 + q * 8) * MPITCH + mt * 16 + l15;
            #pragma unroll
            for (int j = 0; j < 8; j++) bf[j] = base[j * MPITCH];
            acc[0] = __builtin_amdgcn_mfma_f32_16x16x32_bf16(wf[0][ks], bf, acc[0], 0, 0, 0);
            acc[1] = __builtin_amdgcn_mfma_f32_16x16x32_bf16(wf[1][ks], bf, acc[1], 0, 0, 0);
            acc[2] = __builtin_amdgcn_mfma_f32_16x16x32_bf16(wf[2][ks], bf, acc[2], 0, 0, 0);
        }
        for (int nl = 0; nl < 3; nl++)
            #pragma unroll
            for (int reg = 0; reg < 4; reg++) {
                int out = outw + nl * 16 + q * 4 + reg;
                int row = (out < BLK) ? (out << 1) : (((out - BLK) << 1) | 1);
                actB[row * MPITCH + mt * 16 + l15] = f2bf(fmaxf(acc[nl][reg], 0.f));
            }
    }
    __syncthreads();

    // ---- layer 2 ----
    short8 wf2[3][6];
    for (int nl = 0; nl < 3; nl++)
        for (int ks = 0; ks < 6; ks++)
            wf2[nl][ks] = *(const short8*)(WT2 + ((size_t)n * KBIG + outw + nl * 16 + l15) * KBIG + ks * 32 + q * 8);

    for (int mt = 0; mt < 4; mt++) {
        float4v acc[3];
        for (int nl = 0; nl < 3; nl++)
            acc[nl] = *(const float4v*)(bb2 + n * KBIG + outw + nl * 16 + q * 4);
        for (int ks = 0; ks < 6; ks++) {
            short8 bf;
            const short* base = actB + (ks * 32 + q * 8) * MPITCH + mt * 16 + l15;
            #pragma unroll
            for (int j = 0; j < 8; j++) bf[j] = base[j * MPITCH];
            acc[0] = __builtin_amdgcn_mfma_f32_16x16x32_bf16(wf2[0][ks], bf, acc[0], 0, 0, 0);
            acc[1] = __builtin_amdgcn_mfma_f32_16x16x32_bf16(wf2[1][ks], bf, acc[1], 0, 0, 0);
            acc[2] = __builtin_amdgcn_mfma_f32_16x16x32_bf16(wf2[2][ks], bf, acc[2], 0, 0, 0);
        }
        for (int nl = 0; nl < 3; nl++)
            #pragma unroll
            for (int reg = 0; reg < 4; reg++) {
                int out = outw + nl * 16 + q * 4 + reg;
                float v = acc[nl][reg];
                v = copysignf(fmaxf(fabsf(v) - LAM, 0.f), v);
                actA[out * MPITCH + mt * 16 + l15] = f2bf(v);
            }
    }
    __syncthreads();

    // ---- write back: re-interleave rows d (r) and d+96 (i) into words
    {
        const int m = tid & 63;
        const int dr = tid >> 6;          // 0..3
        for (int pass = 0; pass < 24; pass++) {
            int d = dr + pass * 4;
            unsigned short rv = (unsigned short)actA[d * MPITCH + m];
            unsigned short iv = (unsigned short)actA[(d + BLK) * MPITCH + m];
            Xrow0[(size_t)d * MP + m] = (unsigned)rv | ((unsigned)iv << 16);
        }
    }
}

// ---------------------------------------------------------------------------
// K3: inverse rfft per (b,c): Xc -> yT [B*C, S] bf16
// ---------------------------------------------------------------------------
__global__ __launch_bounds__(256) void fft_inv(const unsigned int* __restrict__ Xc,
                                               __hip_bfloat16* __restrict__ yT,
                                               const float2* __restrict__ twf,
                                               const float2* __restrict__ twu) {
    __shared__ float sr[H_LEN];
    __shared__ float si[H_LEN];
    const int wg = blockIdx.x;
    const int tid = threadIdx.x;
    const unsigned int* Xrow = Xc + (size_t)wg * MP;

    const int a = tid & 31, cb3 = tid >> 5;
    for (int it = 0; it < 16; it++) {
        int m = (a << 7) | (it << 3) | cb3;
        unsigned va = Xrow[m];
        int m2 = H_LEN - m;                       // partner (m=0 -> 4096)
        unsigned vb = Xrow[m2];
        float arv = bf2f((unsigned short)(va & 0xFFFF));
        float aiv = bf2f((unsigned short)(va >> 16));
        float brv = bf2f((unsigned short)(vb & 0xFFFF));
        float biv = bf2f((unsigned short)(vb >> 16));
        if (m == 0) { aiv = 0.f; biv = 0.f; }     // numpy irfft drops Im(Y0), Im(YH)
        float er = 0.5f * (arv + brv), ei = 0.5f * (aiv - biv);
        float dr = arv - brv, di = aiv + biv;
        float2 tv = twu[m];
        float wcs = tv.x, wsn = -tv.y;            // ang = +2*pi*m/8192
        float or_ = 0.5f * (wcs * dr - wsn * di);
        float oi = 0.5f * (wcs * di + wsn * dr);
        int r = rev12(m);
        sr[r] = er - oi;
        si[r] = ei + or_;
    }
    __syncthreads();

    // 12 radix-2 DIT stages, inverse (conjugated table twiddles)
    for (int s = 0; s < 12; s++) {
        const int half = 1 << s;
        const float2* tws = twf + (half - 1);
        for (int i = tid; i < H_LEN / 2; i += 256) {
            int j = i & (half - 1);
            int i1 = ((i - j) << 1) + j;
            int i2 = i1 + half;
            float2 wv = tws[j];
            float wcs = wv.x, wsn = -wv.y;        // conjugate: e^{+i}
            float ur = sr[i1], ui = si[i1];
            float vr = sr[i2], vi = si[i2];
            float tr = vr * wcs - vi * wsn;
            float ti = vr * wsn + vi * wcs;
            sr[i1] = ur + tr; si[i1] = ui + ti;
            sr[i2] = ur - tr; si[i2] = ui - ti;
        }
        __syncthreads();
    }

    __hip_bfloat162* orow = (__hip_bfloat162*)(yT + (size_t)wg * S_LEN);
    for (int k = tid; k < H_LEN; k += 256) {
        __hip_bfloat162 v;
        v.x = __float2bfloat16(C_INV * sr[k]);
        v.y = __float2bfloat16(C_INV * si[k]);
        orow[k] = v;
    }
}

// ---------------------------------------------------------------------------
// K4: out[b,s,c] = x[b,s,c] + yT[b*C+c, s]
// ---------------------------------------------------------------------------
__global__ __launch_bounds__(256) void add_out(const __hip_bfloat16* __restrict__ yT,
                                               const float* __restrict__ x,
                                               float* __restrict__ out) {
    __shared__ float t[32][33];
    const int cb = blockIdx.x, sb = blockIdx.y, b = blockIdx.z;
    const int tx = threadIdx.x & 31, ty = threadIdx.x >> 5;
    const __hip_bfloat16* yp = yT + ((size_t)b * HIDDEN + cb * 32) * S_LEN + sb * 32;
    for (int i = 0; i < 4; i++)
        t[ty + 8 * i][tx] = __bfloat162float(yp[(size_t)(ty + 8 * i) * S_LEN + tx]);
    __syncthreads();
    const size_t off = ((size_t)b * S_LEN + sb * 32) * HIDDEN + cb * 32;
    const float* xp = x + off;
    float* op = out + off;
    for (int i = 0; i < 4; i++)
        op[(size_t)(ty + 8 * i) * HIDDEN + tx] =
            xp[(size_t)(ty + 8 * i) * HIDDEN + tx] + t[tx][ty + 8 * i];
}

// ---------------------------------------------------------------------------
extern "C" void kernel_launch(void* const* d_in, const int* in_sizes, int n_in,
                              void* d_out, int out_size, void* d_ws, size_t ws_size,
                              hipStream_t stream) {
    const float* x  = (const float*)d_in[0];
    const float* w1 = (const float*)d_in[1];
    const float* b1 = (const float*)d_in[2];
    const float* w2 = (const float*)d_in[3];
    const float* b2 = (const float*)d_in[4];
    float* out = (float*)d_out;

    // ws layout (all 16B-aligned):
    //   xT/yT  bf16 [B*C, S]              50.33 MB
    //   Xc     u32  [B*C, MP]             51.12 MB
    //   WT1/WT2 bf16 [NB,192,192]         2x0.59 MB
    //   bb1/bb2 f32 [NB,192]              2x6 KB
    //   twf    f32x2 [4095]               32.8 KB
    //   twu    f32x2 [4097]               32.8 KB
    char* p = (char*)d_ws;
    __hip_bfloat16* xT = (__hip_bfloat16*)p;           p += (size_t)BATCH * HIDDEN * S_LEN * 2;
    unsigned int*   Xc = (unsigned int*)p;             p += (size_t)BATCH * HIDDEN * MP * 4;
    short* WT1 = (short*)p;                            p += (size_t)NB * KBIG * KBIG * 2;
    short* WT2 = (short*)p;                            p += (size_t)NB * KBIG * KBIG * 2;
    float* bb1 = (float*)p;                            p += (size_t)NB * KBIG * 4;
    float* bb2 = (float*)p;                            p += (size_t)NB * KBIG * 4;
    float2* twf = (float2*)p;                          p += (size_t)4095 * sizeof(float2);
    float2* twu = (float2*)p;                          p += (size_t)4097 * sizeof(float2);

    prep_tables<<<(H_LEN + 1 + 255) / 256, 256, 0, stream>>>(twf, twu);

    prep_weights<<<(NB * KBIG * KBIG + 255) / 256, 256, 0, stream>>>(
        w1, w2, b1, b2, WT1, WT2, bb1, bb2);

    transpose_in<<<dim3(HIDDEN / 32, S_LEN / 32, BATCH), 256, 0, stream>>>(x, xT);

    fft_fwd<<<BATCH * HIDDEN, 256, 0, stream>>>(xT, Xc, twf, twu);

    mlp_mfma<<<dim3(65, NB, BATCH), 256, 0, stream>>>(WT1, WT2, bb1, bb2, Xc);

    fft_inv<<<BATCH * HIDDEN, 256, 0, stream>>>(Xc, xT /* as yT */, twf, twu);

    add_out<<<dim3(HIDDEN / 32, S_LEN / 32, BATCH), 256, 0, stream>>>(xT, x, out);
}